// Round 7
// baseline (176.070 us; speedup 1.0000x reference)
//
#include <hip/hip_runtime.h>
#include <hip/hip_bf16.h>

// KANLayer: out = (relu(x[:,:,None]*W1+b1) . W2 + b2) @ Wc^T + bc
// B=16384, D=256, H=64, O=256.
// v4: occupancy fix. Grid 1024 (16 B-rows/block), LDS weights back (round-1
//     mechanics) but W1/b1 packed bf16 -> 40KB total LDS -> 4 blocks/CU
//     (16 waves/CU, 2x latency hiding vs v3's grid-capped 8).
#define B_N 16384
#define D_N 256
#define H_N 64
#define O_N 256

typedef __attribute__((ext_vector_type(8))) short short8;
typedef __attribute__((ext_vector_type(4))) short short4v;
typedef __attribute__((ext_vector_type(4))) float f32x4;
typedef __attribute__((ext_vector_type(4))) unsigned int uint4v;

// f32 -> bf16 bits, round-to-nearest-even (finite inputs only)
static __device__ __forceinline__ unsigned short f2bf(float f) {
  unsigned int v = __float_as_uint(f);
  return (unsigned short)((v + 0x7fffu + ((v >> 16) & 1u)) >> 16);
}

__global__ void wc_prep(const float* __restrict__ Wc, unsigned short* __restrict__ o) {
  const int i = (blockIdx.x * 256 + threadIdx.x) * 4;
  const f32x4 v = *reinterpret_cast<const f32x4*>(Wc + i);
  short4v s;
#pragma unroll
  for (int q = 0; q < 4; ++q) s[q] = (short)f2bf(v[q]);
  *reinterpret_cast<short4v*>(o + i) = s;
}

template <bool WCB>
__global__ __launch_bounds__(256, 4) void kan_fused(
    const float* __restrict__ x, const float* __restrict__ W1,
    const float* __restrict__ b1, const float* __restrict__ W2,
    const float* __restrict__ b2, const float* __restrict__ Wc,
    const unsigned short* __restrict__ Wcb, const float* __restrict__ bc,
    float* __restrict__ out) {
  // per-chunk weights, h-index XOR-swizzled by (d&7)<<2 (16B granule):
  __shared__ unsigned int wbs[64 * H_N];   // {bf16(b1)<<16 | bf16(w1)}, 16KB
  __shared__ float        w2s[64 * H_N];   // W2 f32, 16KB
  __shared__ unsigned short uT[16 * 256];  // u tile [row][d] bf16, swizzled, 8KB

  const int tid = threadIdx.x;
  const int dl  = tid & 63;   // lane
  const int wv  = tid >> 6;   // wave id 0..3
  const int b0  = blockIdx.x * 16;

  // ---------------- phase 1: u[b0..b0+15][0..255] ----------------
  for (int c = 0; c < 4; ++c) {
    const int d0 = c * 64;
    // stage: consecutive threads -> consecutive h (coalesced global,
    // conflict-free LDS row writes). Pack w1,b1 to bf16; w2 stays f32.
#pragma unroll
    for (int k = 0; k < 16; ++k) {
      const int i  = tid + k * 256;
      const int dd = i >> 6;
      const int h  = i & 63;
      const int g  = (d0 + dd) * H_N + h;
      const int idx = dd * H_N + (h ^ ((dd & 7) << 2));
      wbs[idx] = (unsigned int)f2bf(W1[g]) | ((unsigned int)f2bf(b1[g]) << 16);
      w2s[idx] = W2[g];
    }
    __syncthreads();

    const int drow = d0 + dl;
    float xv[4], acc[4];
#pragma unroll
    for (int r = 0; r < 4; ++r) {
      xv[r]  = x[(b0 + wv * 4 + r) * D_N + drow];  // coalesced
      acc[r] = 0.f;
    }
    const int swz = (dl & 7) << 2;
#pragma unroll
    for (int h0 = 0; h0 < H_N; h0 += 4) {
      const int hb = dl * H_N + (h0 ^ swz);  // h0%4==0, swizzle hits bits 2-4
      const uint4v wb4 = *reinterpret_cast<const uint4v*>(&wbs[hb]);
      const f32x4  w24 = *reinterpret_cast<const f32x4*>(&w2s[hb]);
#pragma unroll
      for (int k = 0; k < 4; ++k) {
        const float w1f = __uint_as_float(wb4[k] << 16);
        const float b1f = __uint_as_float(wb4[k] & 0xffff0000u);
        const float w2f = w24[k];
#pragma unroll
        for (int r = 0; r < 4; ++r) {
          float t = fmaf(xv[r], w1f, b1f);
          t = fmaxf(t, 0.f);
          acc[r] = fmaf(t, w2f, acc[r]);
        }
      }
    }
    const float bias = b2[drow];
#pragma unroll
    for (int r = 0; r < 4; ++r) {
      const int row = wv * 4 + r;
      int byte = row * 512 + drow * 2;
      byte ^= (row & 7) << 4;  // T2 swizzle for conflict-free MFMA A-reads
      *reinterpret_cast<unsigned short*>(reinterpret_cast<char*>(uT) + byte) =
          f2bf(acc[r] + bias);
    }
    __syncthreads();  // protects wbs/w2s reuse; final one guards phase 2
  }

  // ---------------- phase 2: out[b0..b0+15][:] = u @ Wc^T + bc ----------------
  // wave wv owns N-slice [wv*64, wv*64+64); wave tile M=16 x N=64 -> acc2[4]
  const int n0   = wv * 64;
  const int mrow = dl & 15;
  const int kgrp = dl >> 4;  // 0..3

  f32x4 acc2[4];
#pragma unroll
  for (int j = 0; j < 4; ++j) acc2[j] = (f32x4)(0.f);

#pragma unroll
  for (int ks = 0; ks < 8; ++ks) {
    const int k0 = ks * 32 + kgrp * 8;  // first bf16 k this lane consumes
    // A frag from swizzled LDS u-tile: lane holds u[mrow][k0..k0+7]
    int byte = mrow * 512 + k0 * 2;
    byte ^= (mrow & 7) << 4;
    const short8 afrag = *reinterpret_cast<const short8*>(
        reinterpret_cast<const char*>(uT) + byte);
    // B frags: Wc[n][k0..k0+7] (L2-resident)
    short8 bfrag[4];
#pragma unroll
    for (int j = 0; j < 4; ++j) {
      const int n = n0 + j * 16 + mrow;
      if (WCB) {
        bfrag[j] = *reinterpret_cast<const short8*>(Wcb + n * D_N + k0);
      } else {
        const float* p = Wc + n * D_N + k0;
        const f32x4 lo = *reinterpret_cast<const f32x4*>(p);
        const f32x4 hi = *reinterpret_cast<const f32x4*>(p + 4);
        short8 bf;
#pragma unroll
        for (int q = 0; q < 4; ++q) bf[q] = (short)f2bf(lo[q]);
#pragma unroll
        for (int q = 0; q < 4; ++q) bf[q + 4] = (short)f2bf(hi[q]);
        bfrag[j] = bf;
      }
    }
#pragma unroll
    for (int j = 0; j < 4; ++j)
      acc2[j] = __builtin_amdgcn_mfma_f32_16x16x32_bf16(
          afrag, bfrag[j], acc2[j], 0, 0, 0);
  }

  // epilogue: C/D map col=lane&15, row=4*(lane>>4)+q  (m89-verified)
#pragma unroll
  for (int j = 0; j < 4; ++j) {
    const int colg = n0 + j * 16 + mrow;
    const float bcv = bc[colg];
#pragma unroll
    for (int q = 0; q < 4; ++q) {
      const int rowg = b0 + kgrp * 4 + q;
      out[rowg * O_N + colg] = acc2[j][q] + bcv;
    }
  }
}

extern "C" void kernel_launch(void* const* d_in, const int* in_sizes, int n_in,
                              void* d_out, int out_size, void* d_ws, size_t ws_size,
                              hipStream_t stream) {
  const float* x  = (const float*)d_in[0];
  const float* W1 = (const float*)d_in[1];
  const float* b1 = (const float*)d_in[2];
  const float* W2 = (const float*)d_in[3];
  const float* b2 = (const float*)d_in[4];
  const float* Wc = (const float*)d_in[5];
  const float* bc = (const float*)d_in[6];
  float* out = (float*)d_out;

  if (ws_size >= (size_t)(O_N * D_N * sizeof(unsigned short))) {
    unsigned short* Wcb = (unsigned short*)d_ws;
    wc_prep<<<dim3(O_N * D_N / (256 * 4)), dim3(256), 0, stream>>>(Wc, Wcb);
    kan_fused<true><<<dim3(B_N / 16), dim3(256), 0, stream>>>(
        x, W1, b1, W2, b2, Wc, Wcb, bc, out);
  } else {
    kan_fused<false><<<dim3(B_N / 16), dim3(256), 0, stream>>>(
        x, W1, b1, W2, b2, Wc, (const unsigned short*)nullptr, bc, out);
  }
}

// Round 8
// 126.525 us; speedup vs baseline: 1.3916x; 1.3916x over previous
//
#include <hip/hip_runtime.h>
#include <hip/hip_bf16.h>

// KANLayer: out = (relu(x[:,:,None]*W1+b1) . W2 + b2) @ Wc^T + bc
// B=16384, D=256, H=64, O=256.
// v5: v4 structure (grid 1024, 16 rows/block, 40KB LDS -> 4 blocks/CU) with
//     the register cap REMOVED. v4's launch_bounds(256,4) forced VGPR<=64 and
//     spilled to scratch (+30MB FETCH/WRITE symmetric). (256,2) allows ~256;
//     expected use ~90 <= 128 -> 16 waves/CU via VGPR rule, 4 blocks/CU via LDS.
#define B_N 16384
#define D_N 256
#define H_N 64
#define O_N 256

typedef __attribute__((ext_vector_type(8))) short short8;
typedef __attribute__((ext_vector_type(4))) short short4v;
typedef __attribute__((ext_vector_type(4))) float f32x4;
typedef __attribute__((ext_vector_type(4))) unsigned int uint4v;

// f32 -> bf16 bits, round-to-nearest-even (finite inputs only)
static __device__ __forceinline__ unsigned short f2bf(float f) {
  unsigned int v = __float_as_uint(f);
  return (unsigned short)((v + 0x7fffu + ((v >> 16) & 1u)) >> 16);
}

__global__ void wc_prep(const float* __restrict__ Wc, unsigned short* __restrict__ o) {
  const int i = (blockIdx.x * 256 + threadIdx.x) * 4;
  const f32x4 v = *reinterpret_cast<const f32x4*>(Wc + i);
  short4v s;
#pragma unroll
  for (int q = 0; q < 4; ++q) s[q] = (short)f2bf(v[q]);
  *reinterpret_cast<short4v*>(o + i) = s;
}

template <bool WCB>
__global__ __launch_bounds__(256, 2) void kan_fused(
    const float* __restrict__ x, const float* __restrict__ W1,
    const float* __restrict__ b1, const float* __restrict__ W2,
    const float* __restrict__ b2, const float* __restrict__ Wc,
    const unsigned short* __restrict__ Wcb, const float* __restrict__ bc,
    float* __restrict__ out) {
  // per-chunk weights, h-index XOR-swizzled by (d&7)<<2 (16B granule):
  __shared__ unsigned int wbs[64 * H_N];   // {bf16(b1)<<16 | bf16(w1)}, 16KB
  __shared__ float        w2s[64 * H_N];   // W2 f32, 16KB
  __shared__ unsigned short uT[16 * 256];  // u tile [row][d] bf16, swizzled, 8KB

  const int tid = threadIdx.x;
  const int dl  = tid & 63;   // lane
  const int wv  = tid >> 6;   // wave id 0..3
  const int b0  = blockIdx.x * 16;

  // ---------------- phase 1: u[b0..b0+15][0..255] ----------------
  for (int c = 0; c < 4; ++c) {
    const int d0 = c * 64;
    // stage: consecutive threads -> consecutive h (coalesced global,
    // conflict-free LDS row writes). Pack w1,b1 to bf16; w2 stays f32.
#pragma unroll
    for (int k = 0; k < 16; ++k) {
      const int i  = tid + k * 256;
      const int dd = i >> 6;
      const int h  = i & 63;
      const int g  = (d0 + dd) * H_N + h;
      const int idx = dd * H_N + (h ^ ((dd & 7) << 2));
      wbs[idx] = (unsigned int)f2bf(W1[g]) | ((unsigned int)f2bf(b1[g]) << 16);
      w2s[idx] = W2[g];
    }
    __syncthreads();

    const int drow = d0 + dl;
    float xv[4], acc[4];
#pragma unroll
    for (int r = 0; r < 4; ++r) {
      xv[r]  = x[(b0 + wv * 4 + r) * D_N + drow];  // coalesced
      acc[r] = 0.f;
    }
    const int swz = (dl & 7) << 2;
#pragma unroll
    for (int h0 = 0; h0 < H_N; h0 += 4) {
      const int hb = dl * H_N + (h0 ^ swz);  // h0%4==0, swizzle hits bits 2-4
      const uint4v wb4 = *reinterpret_cast<const uint4v*>(&wbs[hb]);
      const f32x4  w24 = *reinterpret_cast<const f32x4*>(&w2s[hb]);
#pragma unroll
      for (int k = 0; k < 4; ++k) {
        const float w1f = __uint_as_float(wb4[k] << 16);
        const float b1f = __uint_as_float(wb4[k] & 0xffff0000u);
        const float w2f = w24[k];
#pragma unroll
        for (int r = 0; r < 4; ++r) {
          float t = fmaf(xv[r], w1f, b1f);
          t = fmaxf(t, 0.f);
          acc[r] = fmaf(t, w2f, acc[r]);
        }
      }
    }
    const float bias = b2[drow];
#pragma unroll
    for (int r = 0; r < 4; ++r) {
      const int row = wv * 4 + r;
      int byte = row * 512 + drow * 2;
      byte ^= (row & 7) << 4;  // T2 swizzle for conflict-free MFMA A-reads
      *reinterpret_cast<unsigned short*>(reinterpret_cast<char*>(uT) + byte) =
          f2bf(acc[r] + bias);
    }
    __syncthreads();  // protects wbs/w2s reuse; final one guards phase 2
  }

  // ---------------- phase 2: out[b0..b0+15][:] = u @ Wc^T + bc ----------------
  // wave wv owns N-slice [wv*64, wv*64+64); wave tile M=16 x N=64 -> acc2[4]
  const int n0   = wv * 64;
  const int mrow = dl & 15;
  const int kgrp = dl >> 4;  // 0..3

  f32x4 acc2[4];
#pragma unroll
  for (int j = 0; j < 4; ++j) acc2[j] = (f32x4)(0.f);

#pragma unroll
  for (int ks = 0; ks < 8; ++ks) {
    const int k0 = ks * 32 + kgrp * 8;  // first bf16 k this lane consumes
    // A frag from swizzled LDS u-tile: lane holds u[mrow][k0..k0+7]
    int byte = mrow * 512 + k0 * 2;
    byte ^= (mrow & 7) << 4;
    const short8 afrag = *reinterpret_cast<const short8*>(
        reinterpret_cast<const char*>(uT) + byte);
    // B frags: Wc[n][k0..k0+7] (L1/L2-resident, 128KB total)
    short8 bfrag[4];
#pragma unroll
    for (int j = 0; j < 4; ++j) {
      const int n = n0 + j * 16 + mrow;
      if (WCB) {
        bfrag[j] = *reinterpret_cast<const short8*>(Wcb + n * D_N + k0);
      } else {
        const float* p = Wc + n * D_N + k0;
        const f32x4 lo = *reinterpret_cast<const f32x4*>(p);
        const f32x4 hi = *reinterpret_cast<const f32x4*>(p + 4);
        short8 bf;
#pragma unroll
        for (int q = 0; q < 4; ++q) bf[q] = (short)f2bf(lo[q]);
#pragma unroll
        for (int q = 0; q < 4; ++q) bf[q + 4] = (short)f2bf(hi[q]);
        bfrag[j] = bf;
      }
    }
#pragma unroll
    for (int j = 0; j < 4; ++j)
      acc2[j] = __builtin_amdgcn_mfma_f32_16x16x32_bf16(
          afrag, bfrag[j], acc2[j], 0, 0, 0);
  }

  // epilogue: C/D map col=lane&15, row=4*(lane>>4)+q  (m89-verified)
#pragma unroll
  for (int j = 0; j < 4; ++j) {
    const int colg = n0 + j * 16 + mrow;
    const float bcv = bc[colg];
#pragma unroll
    for (int q = 0; q < 4; ++q) {
      const int rowg = b0 + kgrp * 4 + q;
      out[rowg * O_N + colg] = acc2[j][q] + bcv;
    }
  }
}

extern "C" void kernel_launch(void* const* d_in, const int* in_sizes, int n_in,
                              void* d_out, int out_size, void* d_ws, size_t ws_size,
                              hipStream_t stream) {
  const float* x  = (const float*)d_in[0];
  const float* W1 = (const float*)d_in[1];
  const float* b1 = (const float*)d_in[2];
  const float* W2 = (const float*)d_in[3];
  const float* b2 = (const float*)d_in[4];
  const float* Wc = (const float*)d_in[5];
  const float* bc = (const float*)d_in[6];
  float* out = (float*)d_out;

  if (ws_size >= (size_t)(O_N * D_N * sizeof(unsigned short))) {
    unsigned short* Wcb = (unsigned short*)d_ws;
    wc_prep<<<dim3(O_N * D_N / (256 * 4)), dim3(256), 0, stream>>>(Wc, Wcb);
    kan_fused<true><<<dim3(B_N / 16), dim3(256), 0, stream>>>(
        x, W1, b1, W2, b2, Wc, Wcb, bc, out);
  } else {
    kan_fused<false><<<dim3(B_N / 16), dim3(256), 0, stream>>>(
        x, W1, b1, W2, b2, Wc, (const unsigned short*)nullptr, bc, out);
  }
}

// Round 9
// 116.014 us; speedup vs baseline: 1.5177x; 1.0906x over previous
//
#include <hip/hip_runtime.h>
#include <hip/hip_bf16.h>

// KANLayer: out = (relu(x[:,:,None]*W1+b1) . W2 + b2) @ Wc^T + bc
// B=16384, D=256, H=64, O=256.
// v6: kill staging VALU. Prep kernel packs weights (bf16, bank-XOR baked into
//     the GLOBAL layout) into __device__ globals; main kernel stages via
//     global_load_lds DMA (linear copy, zero VALU). LDS 32KB. float2 core.
#define B_N 16384
#define D_N 256
#define H_N 64
#define O_N 256

typedef unsigned int u32;
typedef unsigned short u16;
typedef __attribute__((ext_vector_type(2))) float f32x2;
typedef __attribute__((ext_vector_type(4))) float f32x4;
typedef __attribute__((ext_vector_type(8))) short short8;
typedef __attribute__((ext_vector_type(4))) short short4v;
typedef __attribute__((ext_vector_type(4))) u32 uint4v;
typedef __attribute__((ext_vector_type(2))) u32 uint2v;

// Persistent prepacked weights; rewritten by prep() every launch (idempotent,
// same work every call -> graph-capture safe; no d_ws dependency).
__device__ u32 g_WB[D_N * H_N];       // {bf16(W1)<<16 | bf16(b1)}, h-word XOR (d&7)<<2, 64KB
__device__ u32 g_W2p[D_N * H_N / 2];  // {bf16(W2[2j+1])<<16 | bf16(W2[2j])}, j XOR (d&7)<<1, 32KB
__device__ u16 g_Wcb[O_N * D_N];      // bf16(Wc), natural layout, 128KB

// f32 -> bf16 bits, round-to-nearest-even (finite inputs only)
static __device__ __forceinline__ u16 f2bf(float f) {
  u32 v = __float_as_uint(f);
  return (u16)((v + 0x7fffu + ((v >> 16) & 1u)) >> 16);
}

static __device__ __forceinline__ void dma16(const u32* g, u32* l) {
  // global -> LDS direct copy, 16B/lane; LDS dest = wave-uniform base + lane*16
  __builtin_amdgcn_global_load_lds(
      (const __attribute__((address_space(1))) u32*)g,
      (__attribute__((address_space(3))) u32*)l, 16, 0, 0);
}

__global__ __launch_bounds__(256) void prep(
    const float* __restrict__ W1, const float* __restrict__ b1,
    const float* __restrict__ W2, const float* __restrict__ Wc) {
  const int t = blockIdx.x * 256 + threadIdx.x;  // 16384 threads
  const int d = t >> 6, h = t & 63;
  g_WB[d * 64 + (h ^ ((d & 7) << 2))] =
      ((u32)f2bf(W1[t]) << 16) | (u32)f2bf(b1[t]);
  if ((h & 1) == 0) {
    g_W2p[d * 32 + ((h >> 1) ^ ((d & 7) << 1))] =
        (u32)f2bf(W2[t]) | ((u32)f2bf(W2[t + 1]) << 16);
  }
  const int i = t * 4;  // 65536 Wc elements, 4 per thread
  const f32x4 v = *reinterpret_cast<const f32x4*>(Wc + i);
  short4v s;
#pragma unroll
  for (int q = 0; q < 4; ++q) s[q] = (short)f2bf(v[q]);
  *reinterpret_cast<short4v*>(g_Wcb + i) = s;
}

__global__ __launch_bounds__(256, 2) void kan_fused(
    const float* __restrict__ x, const float* __restrict__ b2,
    const float* __restrict__ bc, float* __restrict__ out) {
  __shared__ u32 wbs[64 * 64];   // 16KB  [d_local][h] (pre-XOR'd layout)
  __shared__ u32 w2p[64 * 32];   // 8KB   [d_local][j] (pre-XOR'd layout)
  __shared__ u16 uT[16 * 256];   // 8KB   u tile [row][d], row-XOR swizzled

  const int tid = threadIdx.x;
  const int dl  = tid & 63;   // lane -> feature d within chunk
  const int wv  = tid >> 6;   // wave 0..3
  const int b0  = blockIdx.x * 16;

  const int wswzb = (dl & 7) << 4;  // byte XOR for wbs reads (w2p uses >>1)

  // ---------------- phase 1: u[b0..b0+15][0..255] ----------------
  for (int c = 0; c < 4; ++c) {
    const int d0 = c * 64, drow = d0 + dl;
    __syncthreads();  // prior chunk's LDS reads done (no-op at c=0)

    const u32* wbg = g_WB  + d0 * 64;  // 16KB chunk, linear
    const u32* w2g = g_W2p + d0 * 32;  // 8KB chunk, linear
#pragma unroll
    for (int i = 0; i < 4; ++i)
      dma16(wbg + (wv * 4 + i) * 256 + dl * 4, wbs + (wv * 4 + i) * 256);
#pragma unroll
    for (int i = 0; i < 2; ++i)
      dma16(w2g + (wv * 2 + i) * 256 + dl * 4, w2p + (wv * 2 + i) * 256);

    // x loads + b2 overlap the DMA flight
    f32x2 xp[2], accp[2];
#pragma unroll
    for (int p = 0; p < 2; ++p) {
      const int row = b0 + wv * 4 + 2 * p;
      xp[p]   = f32x2{x[row * D_N + drow], x[(row + 1) * D_N + drow]};
      accp[p] = f32x2{0.f, 0.f};
    }
    const float b2v = b2[drow];
    __syncthreads();  // DMA landed (barrier drains vmcnt)

    const char* wbbase = (const char*)wbs + dl * 256;
    const char* w2base = (const char*)w2p + dl * 128;
#pragma unroll
    for (int h0 = 0; h0 < H_N; h0 += 4) {
      const int wb_off = (h0 << 2) ^ wswzb;
      const uint4v wb4 = *(const uint4v*)(wbbase + wb_off);
      const uint2v w2w = *(const uint2v*)(w2base + (wb_off >> 1));
#pragma unroll
      for (int k = 0; k < 4; ++k) {
        const float w1f = __uint_as_float(wb4[k] & 0xffff0000u);
        const float b1f = __uint_as_float(wb4[k] << 16);
        const u32 w2word = w2w[k >> 1];
        const float w2f = __uint_as_float((k & 1) ? (w2word & 0xffff0000u)
                                                  : (w2word << 16));
        const f32x2 w1v = {w1f, w1f}, b1v = {b1f, b1f}, w2v = {w2f, w2f};
#pragma unroll
        for (int p = 0; p < 2; ++p) {
          f32x2 tv = __builtin_elementwise_fma(xp[p], w1v, b1v);
          tv = __builtin_elementwise_max(tv, f32x2{0.f, 0.f});
          accp[p] = __builtin_elementwise_fma(tv, w2v, accp[p]);
        }
      }
    }
#pragma unroll
    for (int p = 0; p < 2; ++p)
#pragma unroll
      for (int e = 0; e < 2; ++e) {
        const int row = wv * 4 + 2 * p + e;
        int byte = row * 512 + drow * 2;
        byte ^= (row & 7) << 4;  // T2 swizzle for conflict-free MFMA A-reads
        *(u16*)((char*)uT + byte) = f2bf(accp[p][e] + b2v);
      }
  }
  __syncthreads();

  // ---------------- phase 2: out[b0..b0+15][:] = u @ Wc^T + bc ----------------
  const int n0   = wv * 64;
  const int mrow = dl & 15;
  const int kgrp = dl >> 4;

  f32x4 acc2[4];
#pragma unroll
  for (int j = 0; j < 4; ++j) acc2[j] = (f32x4)(0.f);

#pragma unroll
  for (int ks = 0; ks < 8; ++ks) {
    const int k0 = ks * 32 + kgrp * 8;
    int byte = mrow * 512 + k0 * 2;
    byte ^= (mrow & 7) << 4;
    const short8 afrag = *reinterpret_cast<const short8*>(
        reinterpret_cast<const char*>(uT) + byte);
    short8 bfrag[4];
#pragma unroll
    for (int j = 0; j < 4; ++j)
      bfrag[j] = *reinterpret_cast<const short8*>(
          g_Wcb + (n0 + j * 16 + mrow) * D_N + k0);
#pragma unroll
    for (int j = 0; j < 4; ++j)
      acc2[j] = __builtin_amdgcn_mfma_f32_16x16x32_bf16(
          afrag, bfrag[j], acc2[j], 0, 0, 0);
  }

  // epilogue: C/D map col=lane&15, row=4*(lane>>4)+q  (m89-verified)
#pragma unroll
  for (int j = 0; j < 4; ++j) {
    const int colg = n0 + j * 16 + mrow;
    const float bcv = bc[colg];
#pragma unroll
    for (int q = 0; q < 4; ++q) {
      const int rowg = b0 + kgrp * 4 + q;
      out[rowg * O_N + colg] = acc2[j][q] + bcv;
    }
  }
}

extern "C" void kernel_launch(void* const* d_in, const int* in_sizes, int n_in,
                              void* d_out, int out_size, void* d_ws, size_t ws_size,
                              hipStream_t stream) {
  const float* x  = (const float*)d_in[0];
  const float* W1 = (const float*)d_in[1];
  const float* b1 = (const float*)d_in[2];
  const float* W2 = (const float*)d_in[3];
  const float* b2 = (const float*)d_in[4];
  const float* Wc = (const float*)d_in[5];
  const float* bc = (const float*)d_in[6];
  float* out = (float*)d_out;

  prep<<<dim3(D_N * H_N / 256), dim3(256), 0, stream>>>(W1, b1, W2, Wc);
  kan_fused<<<dim3(B_N / 16), dim3(256), 0, stream>>>(x, b2, bc, out);
}

// Round 10
// 103.699 us; speedup vs baseline: 1.6979x; 1.1187x over previous
//
#include <hip/hip_runtime.h>
#include <hip/hip_bf16.h>
#include <hip/hip_fp16.h>

// KANLayer: out = (relu(x[:,:,None]*W1+b1) . W2 + b2) @ Wc^T + bc
// B=16384, D=256, H=64, O=256.
// v7: thread t owns feature d=t; all 192 weights for that d held in 96 VGPRs
//     as prepacked half2 pairs (zero LDS / zero barriers in phase 1).
//     Core = v_pk_fma_f16 + v_pk_max_f16 + v_dot2_f32_f16 (f32 accumulate):
//     3 insts per 2 h per row, no unpack. Phase 2 = mfma_f32_16x16x32_f16.
#define B_N 16384
#define D_N 256
#define H_N 64
#define O_N 256

typedef unsigned int u32;
typedef unsigned short u16;
typedef _Float16 f16;
typedef __attribute__((ext_vector_type(2))) _Float16 f16x2;
typedef __attribute__((ext_vector_type(8))) _Float16 f16x8;
typedef __attribute__((ext_vector_type(4))) float f32x4;
typedef __attribute__((ext_vector_type(4))) u32 uint4v;
typedef __attribute__((ext_vector_type(4))) u16 u16x4;

// Prepacked weights, rewritten by prep() every launch (idempotent, same work
// each call -> graph-capture safe). Layout [i][d][q]: thread d's 24 dwordx4
// loads are fully coalesced (lane-stride 16B).
__device__ uint4v g_W1p[8 * 256];  // half2{W1[d][8i+2q], W1[d][8i+2q+1]}
__device__ uint4v g_B1p[8 * 256];
__device__ uint4v g_W2p[8 * 256];
__device__ __attribute__((aligned(16))) u16 g_Wch[O_N * D_N];  // f16(Wc), natural

union HU { f16 h; u16 b; };

static __device__ __forceinline__ u32 packh2(float a, float b) {
  f16x2 p = {(f16)a, (f16)b};
  return __builtin_bit_cast(u32, p);
}
static __device__ __forceinline__ u16 f16b(float a) {
  HU u; u.h = (f16)a; return u.b;
}
static __device__ __forceinline__ f16x2 ash2(u32 w) {
  return __builtin_bit_cast(f16x2, w);
}

#if __has_builtin(__builtin_amdgcn_fdot2)
#define FDOT2(a, b, c) __builtin_amdgcn_fdot2((a), (b), (c), false)
#else
#define FDOT2(a, b, c) \
  fmaf((float)(a)[0], (float)(b)[0], fmaf((float)(a)[1], (float)(b)[1], (c)))
#endif

__global__ __launch_bounds__(256) void prep(
    const float* __restrict__ W1, const float* __restrict__ b1,
    const float* __restrict__ W2, const float* __restrict__ Wc) {
  const int u = blockIdx.x * 256 + threadIdx.x;  // 0..16383
  const int d = u >> 6, h = u & 63;
  if ((h & 1) == 0) {
    const int j = h >> 1;  // pair index 0..31
    const int idx = ((j >> 2) * 256 + d) * 4 + (j & 3);
    ((u32*)g_W1p)[idx] = packh2(W1[u], W1[u + 1]);
    ((u32*)g_B1p)[idx] = packh2(b1[u], b1[u + 1]);
    ((u32*)g_W2p)[idx] = packh2(W2[u], W2[u + 1]);
  }
  const int i4 = u * 4;  // 65536 Wc elements, 4/thread
  const f32x4 v = *reinterpret_cast<const f32x4*>(Wc + i4);
  u16x4 s;
#pragma unroll
  for (int q = 0; q < 4; ++q) s[q] = f16b(v[q]);
  *reinterpret_cast<u16x4*>(g_Wch + i4) = s;
}

__global__ __launch_bounds__(256, 3) void kan_fused(
    const float* __restrict__ x, const float* __restrict__ b2,
    const float* __restrict__ bc, float* __restrict__ out) {
  __shared__ u16 uT[16 * 256];  // 8KB f16 u-tile [row][d], row-XOR swizzled

  const int t  = threadIdx.x;   // owns feature d = t
  const int b0 = blockIdx.x * 16;

  // weights -> 96 VGPRs (coalesced dwordx4, L2-resident after first touch)
  uint4v w1r[8], b1r[8], w2r[8];
#pragma unroll
  for (int i = 0; i < 8; ++i) {
    w1r[i] = g_W1p[i * 256 + t];
    b1r[i] = g_B1p[i * 256 + t];
    w2r[i] = g_W2p[i * 256 + t];
  }
  const float b2v = b2[t];

  // ---------------- phase 1: u[b0+row][t], 16 rows, 2 groups of 8 ----------
#pragma unroll
  for (int g = 0; g < 2; ++g) {
    f16x2 xx[8];
    float acc[8];
#pragma unroll
    for (int r = 0; r < 8; ++r) {
      const float xv = x[(b0 + g * 8 + r) * D_N + t];  // coalesced 256B/wave
      xx[r] = (f16x2){(f16)xv, (f16)xv};
      acc[r] = 0.f;
    }
#pragma unroll
    for (int i = 0; i < 8; ++i) {
#pragma unroll
      for (int q = 0; q < 4; ++q) {
        const f16x2 w1 = ash2(w1r[i][q]);
        const f16x2 bb = ash2(b1r[i][q]);
        const f16x2 w2 = ash2(w2r[i][q]);
#pragma unroll
        for (int r = 0; r < 8; ++r) {
          f16x2 tv = __builtin_elementwise_fma(xx[r], w1, bb);  // v_pk_fma_f16
          tv = __builtin_elementwise_max(tv, (f16x2){(f16)0.f, (f16)0.f});
          acc[r] = FDOT2(tv, w2, acc[r]);  // v_dot2_f32_f16, f32 accum
        }
      }
    }
#pragma unroll
    for (int r = 0; r < 8; ++r) {
      const int row = g * 8 + r;
      int byte = row * 512 + t * 2;
      byte ^= (row & 7) << 4;  // T2 swizzle for conflict-free MFMA A-reads
      *(u16*)((char*)uT + byte) = f16b(acc[r] + b2v);
    }
  }
  __syncthreads();  // the only barrier

  // ---------------- phase 2: out[b0..b0+15][:] = u @ Wc^T + bc -------------
  const int wv   = t >> 6;     // wave owns N-slice [wv*64, wv*64+64)
  const int dl   = t & 63;
  const int n0   = wv * 64;
  const int mrow = dl & 15;
  const int kgrp = dl >> 4;

  f32x4 acc2[4];
#pragma unroll
  for (int j = 0; j < 4; ++j) acc2[j] = (f32x4)(0.f);

#pragma unroll
  for (int ks = 0; ks < 8; ++ks) {
    const int k0 = ks * 32 + kgrp * 8;
    int byte = mrow * 512 + k0 * 2;
    byte ^= (mrow & 7) << 4;
    const f16x8 afrag = *reinterpret_cast<const f16x8*>((const char*)uT + byte);
#pragma unroll
    for (int j = 0; j < 4; ++j) {
      const f16x8 bfrag = *reinterpret_cast<const f16x8*>(
          g_Wch + (n0 + j * 16 + mrow) * D_N + k0);
      acc2[j] = __builtin_amdgcn_mfma_f32_16x16x32_f16(afrag, bfrag, acc2[j],
                                                       0, 0, 0);
    }
  }

  // epilogue: C/D map col=lane&15, row=4*(lane>>4)+q (m89-verified)
#pragma unroll
  for (int j = 0; j < 4; ++j) {
    const int colg = n0 + j * 16 + mrow;
    const float bcv = bc[colg];
#pragma unroll
    for (int q = 0; q < 4; ++q) {
      const int rowg = b0 + kgrp * 4 + q;
      out[rowg * O_N + colg] = acc2[j][q] + bcv;
    }
  }
}

extern "C" void kernel_launch(void* const* d_in, const int* in_sizes, int n_in,
                              void* d_out, int out_size, void* d_ws, size_t ws_size,
                              hipStream_t stream) {
  const float* x  = (const float*)d_in[0];
  const float* W1 = (const float*)d_in[1];
  const float* b1 = (const float*)d_in[2];
  const float* W2 = (const float*)d_in[3];
  const float* b2 = (const float*)d_in[4];
  const float* Wc = (const float*)d_in[5];
  const float* bc = (const float*)d_in[6];
  float* out = (float*)d_out;

  prep<<<dim3(D_N * H_N / 256), dim3(256), 0, stream>>>(W1, b1, W2, Wc);
  kan_fused<<<dim3(B_N / 16), dim3(256), 0, stream>>>(x, b2, bc, out);
}